// Round 5
// baseline (446.637 us; speedup 1.0000x reference)
//
#include <hip/hip_runtime.h>
#include <hip/hip_bf16.h>
#include <stdint.h>

#define B_   2
#define N_   20000
#define S_   1024
#define C_   256
#define NS_  16
#define NQ   (B_ * S_)        // 2048 queries
#define M_   (NQ * NS_)       // 32768 MLP rows
#define K1P  288              // 259 padded to multiple of 32
#define O1   512
#define O2   256
#define O3   256
#define OUTC 96

#define R2C   ((float)(0.05 * 0.05))
#define HMINC ((float)(-0.02))
#define HMAXC ((float)(0.04))

__device__ __forceinline__ unsigned short f2b(float f) {
    union { float f; unsigned int i; } x; x.f = f;
    unsigned int r = x.i + 0x7FFFu + ((x.i >> 16) & 1u);   // RNE
    return (unsigned short)(r >> 16);
}
__device__ __forceinline__ float b2f(unsigned short u) {
    union { unsigned int i; float f; } x; x.i = ((unsigned int)u) << 16; return x.f;
}

// ---------------------------------------------------------------- weight prep (fp32 -> bf16)
__global__ __launch_bounds__(256) void pad_w1(const float* __restrict__ w,
                                              unsigned short* __restrict__ wp) {
    int i = blockIdx.x * 256 + threadIdx.x;
    if (i >= O1 * K1P) return;
    int o = i / K1P, k = i - o * K1P;
    wp[i] = (k < 259) ? f2b(w[o * 259 + k]) : (unsigned short)0;
}

__global__ __launch_bounds__(256) void conv_f2b(const float* __restrict__ s,
                                                unsigned short* __restrict__ d, int n) {
    int i = blockIdx.x * 256 + threadIdx.x;
    if (i < n) d[i] = f2b(s[i]);
}

// ---------------------------------------------------------------- cylinder query
// One block per query; 4 waves scan contiguous quarters of N in index order,
// ballot-compact first-16 per wave, merge in wave order (= ascending index).
__global__ __launch_bounds__(256) void cyl_query(const float* __restrict__ xyz,
                                                 const float* __restrict__ new_xyz,
                                                 const float* __restrict__ view_rot,
                                                 int* __restrict__ idx_out) {
#pragma clang fp contract(off)
    int q = blockIdx.x;
    int b = q >> 10;                 // S_ = 1024
    int t = threadIdx.x;
    int w = t >> 6, lane = t & 63;

    __shared__ int lists[4][NS_];
    __shared__ int cnts[4];

    const float* nq = new_xyz + (size_t)q * 3;
    float qx = nq[0], qy = nq[1], qz = nq[2];
    const float* rp = view_rot + (size_t)q * 9;
    float R[9];
#pragma unroll
    for (int i = 0; i < 9; ++i) R[i] = rp[i];
    float dq0 = (R[0]*qx + R[1]*qy) + R[2]*qz;
    float dq1 = (R[3]*qx + R[4]*qy) + R[5]*qz;
    float dq2 = (R[6]*qx + R[7]*qy) + R[8]*qz;

    int start = w * 5000;
    int end   = min(N_, start + 5000);
    int cnt = 0;
    const float* xb = xyz + (size_t)b * N_ * 3;

    for (int base = start; base < end && cnt < NS_; base += 64) {
        int p = base + lane;
        bool m = false;
        if (p < end) {
            const float* pp = xb + (size_t)p * 3;
            float px = pp[0], py = pp[1], pz = pp[2];
            float xr = ((R[0]*px + R[1]*py) + R[2]*pz) - dq0;
            float yr = ((R[3]*px + R[4]*py) + R[5]*pz) - dq1;
            float zr = ((R[6]*px + R[7]*py) + R[8]*pz) - dq2;
            m = ((yr*yr + zr*zr) < R2C) && (xr > HMINC) && (xr < HMAXC);
        }
        unsigned long long bal = __ballot(m);
        int below = __popcll(bal & ((1ull << lane) - 1ull));
        if (m) {
            int pos = cnt + below;
            if (pos < NS_) lists[w][pos] = p;
        }
        cnt += (int)__popcll(bal);
        if (cnt > NS_) cnt = NS_;
    }
    if (lane == 0) cnts[w] = cnt;
    __syncthreads();

    if (t == 0) {
        int buf[NS_]; int total = 0;
        for (int ww = 0; ww < 4 && total < NS_; ++ww)
            for (int i = 0; i < cnts[ww] && total < NS_; ++i)
                buf[total++] = lists[ww][i];
        int first = (total > 0) ? buf[0] : 0;
        for (int i = 0; i < NS_; ++i)
            idx_out[q * NS_ + i] = (i < total) ? buf[i] : first;
    }
}

// ---------------------------------------------------------------- gather + h0 (fp32 in, bf16 out)
// h0 row (q*16+n): [rot_xyz(3) | feat(256) | 0 x29]  (bf16, width 288)
__global__ __launch_bounds__(256) void build_h0(const float* __restrict__ xyz,
                                                const float* __restrict__ new_xyz,
                                                const float* __restrict__ view_rot,
                                                const float* __restrict__ feat,
                                                const int* __restrict__ idxs,
                                                unsigned short* __restrict__ h0) {
#pragma clang fp contract(off)
    int q = blockIdx.x;
    int b = q >> 10;
    int t = threadIdx.x;
    __shared__ int pidx[NS_];
    if (t < NS_) pidx[t] = idxs[q * NS_ + t];
    __syncthreads();

    if (t < NS_) {
        int n = t, p = pidx[n];
        const float* pp = xyz + ((size_t)b * N_ + p) * 3;
        const float* nq = new_xyz + (size_t)q * 3;
        float dx = (pp[0] - nq[0]) / 0.05f;
        float dy = (pp[1] - nq[1]) / 0.05f;
        float dz = (pp[2] - nq[2]) / 0.05f;
        const float* rp = view_rot + (size_t)q * 9;
        // rot_j = sum_k diff_k * R[k][j]
        float r0 = (dx * rp[0] + dy * rp[3]) + dz * rp[6];
        float r1 = (dx * rp[1] + dy * rp[4]) + dz * rp[7];
        float r2 = (dx * rp[2] + dy * rp[5]) + dz * rp[8];
        size_t row = (size_t)(q * NS_ + n) * K1P;
        h0[row + 0] = f2b(r0);
        h0[row + 1] = f2b(r1);
        h0[row + 2] = f2b(r2);
    }
    for (int e = t; e < NS_ * 29; e += 256) {          // zero pad cols 259..287
        int n = e / 29, c = 259 + (e - n * 29);
        h0[(size_t)(q * NS_ + n) * K1P + c] = 0;
    }
    for (int n = 0; n < NS_; ++n) {                    // features, t = channel
        int p = pidx[n];
        h0[(size_t)(q * NS_ + n) * K1P + 3 + t] = f2b(feat[((size_t)b * C_ + t) * N_ + p]);
    }
}

// ---------------------------------------------------------------- MFMA GEMM + BN + ReLU
// C[m,n] = relu( (sum_k A[m,k]*W[n,k] + b[n]) * g[n]/sqrt(1+eps) + be[n] )
typedef float f32x4 __attribute__((ext_vector_type(4)));
typedef short s16x8 __attribute__((ext_vector_type(8)));

__global__ __launch_bounds__(256) void gemm_bn_relu(const unsigned short* __restrict__ A,
                                                    const unsigned short* __restrict__ W,
                                                    const float* __restrict__ bias,
                                                    const float* __restrict__ gam,
                                                    const float* __restrict__ bet,
                                                    unsigned short* __restrict__ out,
                                                    int M, int Nn, int K) {
    __shared__ __align__(16) unsigned short As[128 * 32];
    __shared__ __align__(16) unsigned short Bs[128 * 32];
    int tid  = threadIdx.x;
    int lane = tid & 63, wave = tid >> 6;
    int m0 = blockIdx.x * 128, n0 = blockIdx.y * 128;
    int wm = (wave >> 1) * 64, wn = (wave & 1) * 64;

    f32x4 acc[4][4] = {};

    for (int k0 = 0; k0 < K; k0 += 32) {
        __syncthreads();
#pragma unroll
        for (int j = 0; j < 2; ++j) {
            int e = j * 256 + tid;
            int r = e >> 2, c8 = (e & 3) << 3;
            *(uint4*)&As[e * 8] = *(const uint4*)(A + (size_t)(m0 + r) * K + k0 + c8);
            *(uint4*)&Bs[e * 8] = *(const uint4*)(W + (size_t)(n0 + r) * K + k0 + c8);
        }
        __syncthreads();

        int kq = (lane >> 4) * 8, rr = lane & 15;
        s16x8 af[4], bfr[4];
#pragma unroll
        for (int i = 0; i < 4; ++i) af[i]  = *(const s16x8*)&As[(wm + i * 16 + rr) * 32 + kq];
#pragma unroll
        for (int j = 0; j < 4; ++j) bfr[j] = *(const s16x8*)&Bs[(wn + j * 16 + rr) * 32 + kq];
#pragma unroll
        for (int i = 0; i < 4; ++i)
#pragma unroll
            for (int j = 0; j < 4; ++j)
                acc[i][j] = __builtin_amdgcn_mfma_f32_16x16x32_bf16(af[i], bfr[j], acc[i][j], 0, 0, 0);
    }

    float inv = 1.0f / sqrtf(1.0f + 1e-5f);
    int col = lane & 15, rq = (lane >> 4) * 4;
#pragma unroll
    for (int j = 0; j < 4; ++j) {
        int n = n0 + wn + j * 16 + col;
        float sc = gam[n] * inv;
        float tb = bias[n] * sc + bet[n];
#pragma unroll
        for (int i = 0; i < 4; ++i) {
            int mbase = m0 + wm + i * 16 + rq;
#pragma unroll
            for (int r = 0; r < 4; ++r) {
                float v = acc[i][j][r] * sc + tb;
                v = fmaxf(v, 0.0f);
                out[(size_t)(mbase + r) * Nn + n] = f2b(v);
            }
        }
    }
}

// ---------------------------------------------------------------- maxpool + c1 + c2 + c3 (fp32 out)
__global__ __launch_bounds__(256) void final_head(const unsigned short* __restrict__ h3,
                                                  const float* __restrict__ c1w, const float* __restrict__ c1b,
                                                  const float* __restrict__ c1g, const float* __restrict__ c1be,
                                                  const float* __restrict__ c2w, const float* __restrict__ c2b,
                                                  const float* __restrict__ c2g, const float* __restrict__ c2be,
                                                  const float* __restrict__ c3w, const float* __restrict__ c3b,
                                                  float* __restrict__ out) {
    int q = blockIdx.x, t = threadIdx.x;
    __shared__ float xv[256], yv[256];

    const unsigned short* hb = h3 + (size_t)q * NS_ * 256 + t;
    float mx = 0.0f;   // h3 is post-ReLU, >= 0
#pragma unroll
    for (int n = 0; n < NS_; ++n) mx = fmaxf(mx, b2f(hb[n * 256]));
    xv[t] = mx;
    __syncthreads();

    float inv = 1.0f / sqrtf(1.0f + 1e-5f);
    {   // c1
        const float* wr = c1w + (size_t)t * 256;
        float acc = 0.f;
        for (int c = 0; c < 256; c += 4) {
            float4 u = *(const float4*)(wr + c);
            acc += u.x * xv[c] + u.y * xv[c + 1] + u.z * xv[c + 2] + u.w * xv[c + 3];
        }
        float sc = c1g[t] * inv;
        yv[t] = fmaxf(acc * sc + (c1b[t] * sc + c1be[t]), 0.0f);
    }
    __syncthreads();
    float c2v;
    {   // c2
        const float* wr = c2w + (size_t)t * 256;
        float acc = 0.f;
        for (int c = 0; c < 256; c += 4) {
            float4 u = *(const float4*)(wr + c);
            acc += u.x * yv[c] + u.y * yv[c + 1] + u.z * yv[c + 2] + u.w * yv[c + 3];
        }
        float sc = c2g[t] * inv;
        c2v = fmaxf(acc * sc + (c2b[t] * sc + c2be[t]), 0.0f);
    }
    __syncthreads();
    xv[t] = c2v;
    __syncthreads();
    if (t < OUTC) {   // c3 (no bn/relu) -> fp32 output
        const float* wr = c3w + (size_t)t * 256;
        float acc = 0.f;
        for (int c = 0; c < 256; c += 4) {
            float4 u = *(const float4*)(wr + c);
            acc += u.x * xv[c] + u.y * xv[c + 1] + u.z * xv[c + 2] + u.w * xv[c + 3];
        }
        out[(size_t)q * OUTC + t] = acc + c3b[t];
    }
}

// ---------------------------------------------------------------- launch
extern "C" void kernel_launch(void* const* d_in, const int* in_sizes, int n_in,
                              void* d_out, int out_size, void* d_ws, size_t ws_size,
                              hipStream_t stream) {
    const float* xyz      = (const float*)d_in[0];
    const float* new_xyz  = (const float*)d_in[1];
    const float* view_rot = (const float*)d_in[2];
    const float* feat     = (const float*)d_in[3];
    const float* m1w = (const float*)d_in[4];
    const float* m1b = (const float*)d_in[5];
    const float* m1g = (const float*)d_in[6];
    const float* m1be= (const float*)d_in[7];
    const float* m2w = (const float*)d_in[8];
    const float* m2b = (const float*)d_in[9];
    const float* m2g = (const float*)d_in[10];
    const float* m2be= (const float*)d_in[11];
    const float* m3w = (const float*)d_in[12];
    const float* m3b = (const float*)d_in[13];
    const float* m3g = (const float*)d_in[14];
    const float* m3be= (const float*)d_in[15];
    const float* c1w = (const float*)d_in[16];
    const float* c1b = (const float*)d_in[17];
    const float* c1g = (const float*)d_in[18];
    const float* c1be= (const float*)d_in[19];
    const float* c2w = (const float*)d_in[20];
    const float* c2b = (const float*)d_in[21];
    const float* c2g = (const float*)d_in[22];
    const float* c2be= (const float*)d_in[23];
    const float* c3w = (const float*)d_in[24];
    const float* c3b = (const float*)d_in[25];

    char* ws = (char*)d_ws;
    // layout (16B-aligned):
    //   [0, 131072)            idx  (2048*16 int32)
    //   [131072, 425984)       W1 padded bf16 (512*288)
    //   [425984, 688128)       W2 bf16 (256*512)
    //   [688128, 819200)       W3 bf16 (256*256)
    //   [819200, 19693568)     h0 (32768*288 bf16) -> reused as h2 (32768*256)
    //   [19693568, 53248000)   h1 (32768*512 bf16) -> reused as h3 (32768*256)
    int*            idxs = (int*)ws;
    unsigned short* w1p  = (unsigned short*)(ws + 131072);
    unsigned short* w2p  = (unsigned short*)(ws + 425984);
    unsigned short* w3p  = (unsigned short*)(ws + 688128);
    unsigned short* h0   = (unsigned short*)(ws + 819200);
    unsigned short* h1   = (unsigned short*)(ws + 19693568);
    unsigned short* h2   = h0;   // h0 dead after L1
    unsigned short* h3   = h1;   // h1 dead after L2

    hipLaunchKernelGGL(pad_w1, dim3((O1 * K1P) / 256), dim3(256), 0, stream, m1w, w1p);
    hipLaunchKernelGGL(conv_f2b, dim3((O2 * 512) / 256), dim3(256), 0, stream, m2w, w2p, O2 * 512);
    hipLaunchKernelGGL(conv_f2b, dim3((O3 * 256) / 256), dim3(256), 0, stream, m3w, w3p, O3 * 256);
    hipLaunchKernelGGL(cyl_query, dim3(NQ), dim3(256), 0, stream, xyz, new_xyz, view_rot, idxs);
    hipLaunchKernelGGL(build_h0, dim3(NQ), dim3(256), 0, stream, xyz, new_xyz, view_rot, feat, idxs, h0);
    hipLaunchKernelGGL(gemm_bn_relu, dim3(M_ / 128, O1 / 128), dim3(256), 0, stream,
                       h0, w1p, m1b, m1g, m1be, h1, M_, O1, K1P);
    hipLaunchKernelGGL(gemm_bn_relu, dim3(M_ / 128, O2 / 128), dim3(256), 0, stream,
                       h1, w2p, m2b, m2g, m2be, h2, M_, O2, 512);
    hipLaunchKernelGGL(gemm_bn_relu, dim3(M_ / 128, O3 / 128), dim3(256), 0, stream,
                       h2, w3p, m3b, m3g, m3be, h3, M_, O3, 256);
    hipLaunchKernelGGL(final_head, dim3(NQ), dim3(256), 0, stream,
                       h3, c1w, c1b, c1g, c1be, c2w, c2b, c2g, c2be, c3w, c3b,
                       (float*)d_out);
}

// Round 6
// 324.427 us; speedup vs baseline: 1.3767x; 1.3767x over previous
//
#include <hip/hip_runtime.h>
#include <hip/hip_bf16.h>
#include <stdint.h>

#define B_   2
#define N_   20000
#define S_   1024
#define C_   256
#define NS_  16
#define NQ   (B_ * S_)        // 2048 queries
#define M_   (NQ * NS_)       // 32768 MLP rows
#define K1P  288              // 259 padded to multiple of 32
#define O1   512
#define O2   256
#define O3   256
#define OUTC 96

#define R2C   ((float)(0.05 * 0.05))
#define HMINC ((float)(-0.02))
#define HMAXC ((float)(0.04))

__device__ __forceinline__ unsigned short f2b(float f) {
    union { float f; unsigned int i; } x; x.f = f;
    unsigned int r = x.i + 0x7FFFu + ((x.i >> 16) & 1u);   // RNE
    return (unsigned short)(r >> 16);
}
__device__ __forceinline__ float b2f(unsigned short u) {
    union { unsigned int i; float f; } x; x.i = ((unsigned int)u) << 16; return x.f;
}

// ---------------------------------------------------------------- weight prep stage 1 (fp32 -> bf16)
// [0,147456): m1w pad 259->288 | [147456,278528): m2w | [278528,344064): m3w
__global__ __launch_bounds__(256) void prep_w123(const float* __restrict__ m1w,
                                                 const float* __restrict__ m2w,
                                                 const float* __restrict__ m3w,
                                                 unsigned short* __restrict__ w1p,
                                                 unsigned short* __restrict__ w2p,
                                                 unsigned short* __restrict__ w3p) {
    int i = blockIdx.x * 256 + threadIdx.x;
    if (i < O1 * K1P) {
        int o = i / K1P, k = i - o * K1P;
        w1p[i] = (k < 259) ? f2b(m1w[o * 259 + k]) : (unsigned short)0;
    } else if (i < O1 * K1P + O2 * 512) {
        int j = i - O1 * K1P;
        w2p[j] = f2b(m2w[j]);
    } else if (i < O1 * K1P + O2 * 512 + O3 * 256) {
        int j = i - O1 * K1P - O2 * 512;
        w3p[j] = f2b(m3w[j]);
    }
}

// ---------------------------------------------------------------- weight prep stage 2 (head)
// [0,65536): c1w | [65536,131072): c2w | [131072,163840): c3w pad 96->128 rows
__global__ __launch_bounds__(256) void prep_head_w(const float* __restrict__ c1w,
                                                   const float* __restrict__ c2w,
                                                   const float* __restrict__ c3w,
                                                   unsigned short* __restrict__ c1wb,
                                                   unsigned short* __restrict__ c2wb,
                                                   unsigned short* __restrict__ c3wb) {
    int i = blockIdx.x * 256 + threadIdx.x;
    if (i < 65536) {
        c1wb[i] = f2b(c1w[i]);
    } else if (i < 131072) {
        c2wb[i - 65536] = f2b(c2w[i - 65536]);
    } else if (i < 163840) {
        int j = i - 131072;
        int o = j >> 8, k = j & 255;
        c3wb[j] = (o < OUTC) ? f2b(c3w[o * 256 + k]) : (unsigned short)0;
    }
}

// ---------------------------------------------------------------- cylinder query
__global__ __launch_bounds__(256) void cyl_query(const float* __restrict__ xyz,
                                                 const float* __restrict__ new_xyz,
                                                 const float* __restrict__ view_rot,
                                                 int* __restrict__ idx_out) {
#pragma clang fp contract(off)
    int q = blockIdx.x;
    int b = q >> 10;                 // S_ = 1024
    int t = threadIdx.x;
    int w = t >> 6, lane = t & 63;

    __shared__ int lists[4][NS_];
    __shared__ int cnts[4];

    const float* nq = new_xyz + (size_t)q * 3;
    float qx = nq[0], qy = nq[1], qz = nq[2];
    const float* rp = view_rot + (size_t)q * 9;
    float R[9];
#pragma unroll
    for (int i = 0; i < 9; ++i) R[i] = rp[i];
    float dq0 = (R[0]*qx + R[1]*qy) + R[2]*qz;
    float dq1 = (R[3]*qx + R[4]*qy) + R[5]*qz;
    float dq2 = (R[6]*qx + R[7]*qy) + R[8]*qz;

    int start = w * 5000;
    int end   = min(N_, start + 5000);
    int cnt = 0;
    const float* xb = xyz + (size_t)b * N_ * 3;

    for (int base = start; base < end && cnt < NS_; base += 64) {
        int p = base + lane;
        bool m = false;
        if (p < end) {
            const float* pp = xb + (size_t)p * 3;
            float px = pp[0], py = pp[1], pz = pp[2];
            float xr = ((R[0]*px + R[1]*py) + R[2]*pz) - dq0;
            float yr = ((R[3]*px + R[4]*py) + R[5]*pz) - dq1;
            float zr = ((R[6]*px + R[7]*py) + R[8]*pz) - dq2;
            m = ((yr*yr + zr*zr) < R2C) && (xr > HMINC) && (xr < HMAXC);
        }
        unsigned long long bal = __ballot(m);
        int below = __popcll(bal & ((1ull << lane) - 1ull));
        if (m) {
            int pos = cnt + below;
            if (pos < NS_) lists[w][pos] = p;
        }
        cnt += (int)__popcll(bal);
        if (cnt > NS_) cnt = NS_;
    }
    if (lane == 0) cnts[w] = cnt;
    __syncthreads();

    if (t == 0) {
        int buf[NS_]; int total = 0;
        for (int ww = 0; ww < 4 && total < NS_; ++ww)
            for (int i = 0; i < cnts[ww] && total < NS_; ++i)
                buf[total++] = lists[ww][i];
        int first = (total > 0) ? buf[0] : 0;
        for (int i = 0; i < NS_; ++i)
            idx_out[q * NS_ + i] = (i < total) ? buf[i] : first;
    }
}

// ---------------------------------------------------------------- gather + h0 (fp32 in, bf16 out)
// h0 row (q*16+n): [rot_xyz(3) | feat(256) | 0 x29]  (bf16, width 288)
__global__ __launch_bounds__(256) void build_h0(const float* __restrict__ xyz,
                                                const float* __restrict__ new_xyz,
                                                const float* __restrict__ view_rot,
                                                const float* __restrict__ feat,
                                                const int* __restrict__ idxs,
                                                unsigned short* __restrict__ h0) {
#pragma clang fp contract(off)
    int q = blockIdx.x;
    int b = q >> 10;
    int t = threadIdx.x;
    __shared__ int pidx[NS_];
    if (t < NS_) pidx[t] = idxs[q * NS_ + t];
    __syncthreads();

    if (t < NS_) {
        int n = t, p = pidx[n];
        const float* pp = xyz + ((size_t)b * N_ + p) * 3;
        const float* nq = new_xyz + (size_t)q * 3;
        float dx = (pp[0] - nq[0]) / 0.05f;
        float dy = (pp[1] - nq[1]) / 0.05f;
        float dz = (pp[2] - nq[2]) / 0.05f;
        const float* rp = view_rot + (size_t)q * 9;
        // rot_j = sum_k diff_k * R[k][j]
        float r0 = (dx * rp[0] + dy * rp[3]) + dz * rp[6];
        float r1 = (dx * rp[1] + dy * rp[4]) + dz * rp[7];
        float r2 = (dx * rp[2] + dy * rp[5]) + dz * rp[8];
        size_t row = (size_t)(q * NS_ + n) * K1P;
        h0[row + 0] = f2b(r0);
        h0[row + 1] = f2b(r1);
        h0[row + 2] = f2b(r2);
    }
    for (int e = t; e < NS_ * 29; e += 256) {          // zero pad cols 259..287
        int n = e / 29, c = 259 + (e - n * 29);
        h0[(size_t)(q * NS_ + n) * K1P + c] = 0;
    }
    for (int n = 0; n < NS_; ++n) {                    // features, t = channel
        int p = pidx[n];
        h0[(size_t)(q * NS_ + n) * K1P + 3 + t] = f2b(feat[((size_t)b * C_ + t) * N_ + p]);
    }
}

// ---------------------------------------------------------------- MFMA GEMM + BN + ReLU
// C[m,n] = relu( (sum_k A[m,k]*W[n,k] + b[n]) * g[n]/sqrt(1+eps) + be[n] )
typedef float f32x4 __attribute__((ext_vector_type(4)));
typedef short s16x8 __attribute__((ext_vector_type(8)));

__global__ __launch_bounds__(256) void gemm_bn_relu(const unsigned short* __restrict__ A,
                                                    const unsigned short* __restrict__ W,
                                                    const float* __restrict__ bias,
                                                    const float* __restrict__ gam,
                                                    const float* __restrict__ bet,
                                                    unsigned short* __restrict__ out,
                                                    int M, int Nn, int K) {
    __shared__ __align__(16) unsigned short As[128 * 32];
    __shared__ __align__(16) unsigned short Bs[128 * 32];
    int tid  = threadIdx.x;
    int lane = tid & 63, wave = tid >> 6;
    int m0 = blockIdx.x * 128, n0 = blockIdx.y * 128;
    int wm = (wave >> 1) * 64, wn = (wave & 1) * 64;

    f32x4 acc[4][4] = {};

    for (int k0 = 0; k0 < K; k0 += 32) {
        __syncthreads();
#pragma unroll
        for (int j = 0; j < 2; ++j) {
            int e = j * 256 + tid;
            int r = e >> 2, c8 = (e & 3) << 3;
            *(uint4*)&As[e * 8] = *(const uint4*)(A + (size_t)(m0 + r) * K + k0 + c8);
            *(uint4*)&Bs[e * 8] = *(const uint4*)(W + (size_t)(n0 + r) * K + k0 + c8);
        }
        __syncthreads();

        int kq = (lane >> 4) * 8, rr = lane & 15;
        s16x8 af[4], bfr[4];
#pragma unroll
        for (int i = 0; i < 4; ++i) af[i]  = *(const s16x8*)&As[(wm + i * 16 + rr) * 32 + kq];
#pragma unroll
        for (int j = 0; j < 4; ++j) bfr[j] = *(const s16x8*)&Bs[(wn + j * 16 + rr) * 32 + kq];
#pragma unroll
        for (int i = 0; i < 4; ++i)
#pragma unroll
            for (int j = 0; j < 4; ++j)
                acc[i][j] = __builtin_amdgcn_mfma_f32_16x16x32_bf16(af[i], bfr[j], acc[i][j], 0, 0, 0);
    }

    float inv = 1.0f / sqrtf(1.0f + 1e-5f);
    int col = lane & 15, rq = (lane >> 4) * 4;
#pragma unroll
    for (int j = 0; j < 4; ++j) {
        int n = n0 + wn + j * 16 + col;
        float sc = gam[n] * inv;
        float tb = bias[n] * sc + bet[n];
#pragma unroll
        for (int i = 0; i < 4; ++i) {
            int mbase = m0 + wm + i * 16 + rq;
#pragma unroll
            for (int r = 0; r < 4; ++r) {
                float v = acc[i][j][r] * sc + tb;
                v = fmaxf(v, 0.0f);
                out[(size_t)(mbase + r) * Nn + n] = f2b(v);
            }
        }
    }
}

// ---------------------------------------------------------------- MFMA GEMM + BN + ReLU + 16-row maxpool
// Same as gemm_bn_relu but output is max over groups of 16 consecutive m rows
// (one query per 16 rows; 16-row groups align exactly with i-tiles).
// hp[m/16][n] = max_{r in group} relu(bn(acc))
__global__ __launch_bounds__(256) void gemm_bn_relu_maxpool(const unsigned short* __restrict__ A,
                                                            const unsigned short* __restrict__ W,
                                                            const float* __restrict__ bias,
                                                            const float* __restrict__ gam,
                                                            const float* __restrict__ bet,
                                                            unsigned short* __restrict__ hp,
                                                            int M, int Nn, int K) {
    __shared__ __align__(16) unsigned short As[128 * 32];
    __shared__ __align__(16) unsigned short Bs[128 * 32];
    int tid  = threadIdx.x;
    int lane = tid & 63, wave = tid >> 6;
    int m0 = blockIdx.x * 128, n0 = blockIdx.y * 128;
    int wm = (wave >> 1) * 64, wn = (wave & 1) * 64;

    f32x4 acc[4][4] = {};

    for (int k0 = 0; k0 < K; k0 += 32) {
        __syncthreads();
#pragma unroll
        for (int j = 0; j < 2; ++j) {
            int e = j * 256 + tid;
            int r = e >> 2, c8 = (e & 3) << 3;
            *(uint4*)&As[e * 8] = *(const uint4*)(A + (size_t)(m0 + r) * K + k0 + c8);
            *(uint4*)&Bs[e * 8] = *(const uint4*)(W + (size_t)(n0 + r) * K + k0 + c8);
        }
        __syncthreads();

        int kq = (lane >> 4) * 8, rr = lane & 15;
        s16x8 af[4], bfr[4];
#pragma unroll
        for (int i = 0; i < 4; ++i) af[i]  = *(const s16x8*)&As[(wm + i * 16 + rr) * 32 + kq];
#pragma unroll
        for (int j = 0; j < 4; ++j) bfr[j] = *(const s16x8*)&Bs[(wn + j * 16 + rr) * 32 + kq];
#pragma unroll
        for (int i = 0; i < 4; ++i)
#pragma unroll
            for (int j = 0; j < 4; ++j)
                acc[i][j] = __builtin_amdgcn_mfma_f32_16x16x32_bf16(af[i], bfr[j], acc[i][j], 0, 0, 0);
    }

    float inv = 1.0f / sqrtf(1.0f + 1e-5f);
    int col = lane & 15;
    int qbase = (m0 + wm) >> 4;                 // query index of i-tile 0
#pragma unroll
    for (int j = 0; j < 4; ++j) {
        int n = n0 + wn + j * 16 + col;
        float sc = gam[n] * inv;
        float tb = bias[n] * sc + bet[n];
#pragma unroll
        for (int i = 0; i < 4; ++i) {
            float mx = 0.0f;                    // relu floor
#pragma unroll
            for (int r = 0; r < 4; ++r)
                mx = fmaxf(mx, acc[i][j][r] * sc + tb);
            // reduce across the 4 quads (rows rq..rq+3 each)
            mx = fmaxf(mx, __shfl_xor(mx, 16, 64));
            mx = fmaxf(mx, __shfl_xor(mx, 32, 64));
            if (lane < 16)
                hp[(size_t)(qbase + i) * Nn + n] = f2b(mx);
        }
    }
}

// ---------------------------------------------------------------- c3 GEMM: fp32 out, no BN/relu, N=96 (padded 128)
__global__ __launch_bounds__(256) void gemm_c3(const unsigned short* __restrict__ A,
                                               const unsigned short* __restrict__ W,
                                               const float* __restrict__ bias,
                                               float* __restrict__ out,
                                               int M, int K) {
    __shared__ __align__(16) unsigned short As[128 * 32];
    __shared__ __align__(16) unsigned short Bs[128 * 32];
    int tid  = threadIdx.x;
    int lane = tid & 63, wave = tid >> 6;
    int m0 = blockIdx.x * 128;
    int wm = (wave >> 1) * 64, wn = (wave & 1) * 64;

    f32x4 acc[4][4] = {};

    for (int k0 = 0; k0 < K; k0 += 32) {
        __syncthreads();
#pragma unroll
        for (int j = 0; j < 2; ++j) {
            int e = j * 256 + tid;
            int r = e >> 2, c8 = (e & 3) << 3;
            *(uint4*)&As[e * 8] = *(const uint4*)(A + (size_t)(m0 + r) * K + k0 + c8);
            *(uint4*)&Bs[e * 8] = *(const uint4*)(W + (size_t)r * K + k0 + c8);
        }
        __syncthreads();

        int kq = (lane >> 4) * 8, rr = lane & 15;
        s16x8 af[4], bfr[4];
#pragma unroll
        for (int i = 0; i < 4; ++i) af[i]  = *(const s16x8*)&As[(wm + i * 16 + rr) * 32 + kq];
#pragma unroll
        for (int j = 0; j < 4; ++j) bfr[j] = *(const s16x8*)&Bs[(wn + j * 16 + rr) * 32 + kq];
#pragma unroll
        for (int i = 0; i < 4; ++i)
#pragma unroll
            for (int j = 0; j < 4; ++j)
                acc[i][j] = __builtin_amdgcn_mfma_f32_16x16x32_bf16(af[i], bfr[j], acc[i][j], 0, 0, 0);
    }

    int col = lane & 15, rq = (lane >> 4) * 4;
#pragma unroll
    for (int j = 0; j < 4; ++j) {
        int n = wn + j * 16 + col;
        if (n >= OUTC) continue;
        float bb = bias[n];
#pragma unroll
        for (int i = 0; i < 4; ++i) {
            int mbase = m0 + wm + i * 16 + rq;
#pragma unroll
            for (int r = 0; r < 4; ++r)
                out[(size_t)(mbase + r) * OUTC + n] = acc[i][j][r] + bb;
        }
    }
}

// ---------------------------------------------------------------- launch
extern "C" void kernel_launch(void* const* d_in, const int* in_sizes, int n_in,
                              void* d_out, int out_size, void* d_ws, size_t ws_size,
                              hipStream_t stream) {
    const float* xyz      = (const float*)d_in[0];
    const float* new_xyz  = (const float*)d_in[1];
    const float* view_rot = (const float*)d_in[2];
    const float* feat     = (const float*)d_in[3];
    const float* m1w = (const float*)d_in[4];
    const float* m1b = (const float*)d_in[5];
    const float* m1g = (const float*)d_in[6];
    const float* m1be= (const float*)d_in[7];
    const float* m2w = (const float*)d_in[8];
    const float* m2b = (const float*)d_in[9];
    const float* m2g = (const float*)d_in[10];
    const float* m2be= (const float*)d_in[11];
    const float* m3w = (const float*)d_in[12];
    const float* m3b = (const float*)d_in[13];
    const float* m3g = (const float*)d_in[14];
    const float* m3be= (const float*)d_in[15];
    const float* c1w = (const float*)d_in[16];
    const float* c1b = (const float*)d_in[17];
    const float* c1g = (const float*)d_in[18];
    const float* c1be= (const float*)d_in[19];
    const float* c2w = (const float*)d_in[20];
    const float* c2b = (const float*)d_in[21];
    const float* c2g = (const float*)d_in[22];
    const float* c2be= (const float*)d_in[23];
    const float* c3w = (const float*)d_in[24];
    const float* c3b = (const float*)d_in[25];

    char* ws = (char*)d_ws;
    // layout (16B-aligned), total 53,248,000 B (same as round 5):
    //   [0, 131072)            idx  (2048*16 int32)
    //   [131072, 425984)       W1 padded bf16 (512*288)
    //   [425984, 688128)       W2 bf16 (256*512)
    //   [688128, 819200)       W3 bf16 (256*256)
    //   [819200, 19693568)     h0 (32768*288 bf16) -> reused as h2 (32768*256)
    //   [19693568, 53248000)   h1 (32768*512 bf16); after gemm2 h1 is dead and hosts:
    //       +0        hp  (2048*256 bf16, 1 MB)
    //       +4 MB     g1  (2048*256 bf16, 1 MB)
    //       +8 MB     g2  (2048*256 bf16, 1 MB)
    //       +12 MB    c1wb (256*256 bf16)
    //       +13 MB    c2wb (256*256 bf16)
    //       +14 MB    c3wb (128*256 bf16)
    int*            idxs = (int*)ws;
    unsigned short* w1p  = (unsigned short*)(ws + 131072);
    unsigned short* w2p  = (unsigned short*)(ws + 425984);
    unsigned short* w3p  = (unsigned short*)(ws + 688128);
    unsigned short* h0   = (unsigned short*)(ws + 819200);
    char*           h1b  = ws + 19693568;
    unsigned short* h1   = (unsigned short*)h1b;
    unsigned short* h2   = h0;   // h0 dead after gemm1
    unsigned short* hp   = (unsigned short*)(h1b + 0);
    unsigned short* g1   = (unsigned short*)(h1b + 4194304);
    unsigned short* g2   = (unsigned short*)(h1b + 8388608);
    unsigned short* c1wb = (unsigned short*)(h1b + 12582912);
    unsigned short* c2wb = (unsigned short*)(h1b + 13631488);
    unsigned short* c3wb = (unsigned short*)(h1b + 14680064);

    hipLaunchKernelGGL(prep_w123, dim3((O1 * K1P + O2 * 512 + O3 * 256) / 256), dim3(256), 0, stream,
                       m1w, m2w, m3w, w1p, w2p, w3p);
    hipLaunchKernelGGL(cyl_query, dim3(NQ), dim3(256), 0, stream, xyz, new_xyz, view_rot, idxs);
    hipLaunchKernelGGL(build_h0, dim3(NQ), dim3(256), 0, stream, xyz, new_xyz, view_rot, feat, idxs, h0);
    hipLaunchKernelGGL(gemm_bn_relu, dim3(M_ / 128, O1 / 128), dim3(256), 0, stream,
                       h0, w1p, m1b, m1g, m1be, h1, M_, O1, K1P);
    hipLaunchKernelGGL(gemm_bn_relu, dim3(M_ / 128, O2 / 128), dim3(256), 0, stream,
                       h1, w2p, m2b, m2g, m2be, h2, M_, O2, 512);
    hipLaunchKernelGGL(prep_head_w, dim3(163840 / 256), dim3(256), 0, stream,
                       c1w, c2w, c3w, c1wb, c2wb, c3wb);
    hipLaunchKernelGGL(gemm_bn_relu_maxpool, dim3(M_ / 128, O3 / 128), dim3(256), 0, stream,
                       h2, w3p, m3b, m3g, m3be, hp, M_, O3, 256);
    hipLaunchKernelGGL(gemm_bn_relu, dim3(NQ / 128, 256 / 128), dim3(256), 0, stream,
                       hp, c1wb, c1b, c1g, c1be, g1, NQ, 256, 256);
    hipLaunchKernelGGL(gemm_bn_relu, dim3(NQ / 128, 256 / 128), dim3(256), 0, stream,
                       g1, c2wb, c2b, c2g, c2be, g2, NQ, 256, 256);
    hipLaunchKernelGGL(gemm_c3, dim3(NQ / 128), dim3(256), 0, stream,
                       g2, c3wb, c3b, (float*)d_out, NQ, 256);
}

// Round 7
// 269.359 us; speedup vs baseline: 1.6581x; 1.2044x over previous
//
#include <hip/hip_runtime.h>
#include <hip/hip_bf16.h>
#include <stdint.h>

#define B_   2
#define N_   20000
#define S_   1024
#define C_   256
#define NS_  16
#define NQ   (B_ * S_)        // 2048 queries
#define M_   (NQ * NS_)       // 32768 MLP rows
#define K1P  288              // 259 padded to multiple of 32
#define O1   512
#define O2   256
#define O3   256
#define OUTC 96

#define R2C   ((float)(0.05 * 0.05))
#define HMINC ((float)(-0.02))
#define HMAXC ((float)(0.04))

__device__ __forceinline__ unsigned short f2b(float f) {
    union { float f; unsigned int i; } x; x.f = f;
    unsigned int r = x.i + 0x7FFFu + ((x.i >> 16) & 1u);   // RNE
    return (unsigned short)(r >> 16);
}
__device__ __forceinline__ float b2f(unsigned short u) {
    union { unsigned int i; float f; } x; x.i = ((unsigned int)u) << 16; return x.f;
}

// ---------------------------------------------------------------- weight prep stage 1 (fp32 -> bf16)
// W1 column-permuted to match h0 layout [feat(256) | rot(3) | pad(29)]:
//   k<256 -> m1w[o][3+k], k in 256..258 -> m1w[o][k-256], else 0
__global__ __launch_bounds__(256) void prep_w123(const float* __restrict__ m1w,
                                                 const float* __restrict__ m2w,
                                                 const float* __restrict__ m3w,
                                                 unsigned short* __restrict__ w1p,
                                                 unsigned short* __restrict__ w2p,
                                                 unsigned short* __restrict__ w3p) {
    int i = blockIdx.x * 256 + threadIdx.x;
    if (i < O1 * K1P) {
        int o = i / K1P, k = i - o * K1P;
        float v = 0.0f;
        if (k < 256)      v = m1w[o * 259 + 3 + k];
        else if (k < 259) v = m1w[o * 259 + (k - 256)];
        w1p[i] = (k < 259) ? f2b(v) : (unsigned short)0;
    } else if (i < O1 * K1P + O2 * 512) {
        int j = i - O1 * K1P;
        w2p[j] = f2b(m2w[j]);
    } else if (i < O1 * K1P + O2 * 512 + O3 * 256) {
        int j = i - O1 * K1P - O2 * 512;
        w3p[j] = f2b(m3w[j]);
    }
}

// ---------------------------------------------------------------- weight prep stage 2 (head)
__global__ __launch_bounds__(256) void prep_head_w(const float* __restrict__ c1w,
                                                   const float* __restrict__ c2w,
                                                   const float* __restrict__ c3w,
                                                   unsigned short* __restrict__ c1wb,
                                                   unsigned short* __restrict__ c2wb,
                                                   unsigned short* __restrict__ c3wb) {
    int i = blockIdx.x * 256 + threadIdx.x;
    if (i < 65536) {
        c1wb[i] = f2b(c1w[i]);
    } else if (i < 131072) {
        c2wb[i - 65536] = f2b(c2w[i - 65536]);
    } else if (i < 163840) {
        int j = i - 131072;
        int o = j >> 8, k = j & 255;
        c3wb[j] = (o < OUTC) ? f2b(c3w[o * 256 + k]) : (unsigned short)0;
    }
}

// ---------------------------------------------------------------- feature transpose [B][C][N] fp32 -> [B][N][C] bf16
// 32x32 tiles via LDS; N_=20000=32*625 exact. All LDS phases <=2-way aliasing (free).
__global__ __launch_bounds__(256) void transpose_feat(const float* __restrict__ feat,
                                                      unsigned short* __restrict__ feat_t) {
    __shared__ float tile[32][33];
    int n0 = blockIdx.x * 32, c0 = blockIdx.y * 32, b = blockIdx.z;
    int t = threadIdx.x;
    int nl = t & 31;
#pragma unroll
    for (int i = 0; i < 4; ++i) {
        int cl = (t >> 5) + i * 8;
        tile[cl][nl] = feat[((size_t)(b * C_ + c0 + cl)) * N_ + n0 + nl];
    }
    __syncthreads();
    int nr = t >> 3, c4 = (t & 7) * 4;
    ushort4 v;
    v.x = f2b(tile[c4 + 0][nr]);
    v.y = f2b(tile[c4 + 1][nr]);
    v.z = f2b(tile[c4 + 2][nr]);
    v.w = f2b(tile[c4 + 3][nr]);
    *(ushort4*)(feat_t + ((size_t)(b * N_ + n0 + nr)) * C_ + c0 + c4) = v;
}

// ---------------------------------------------------------------- cylinder query
__global__ __launch_bounds__(256) void cyl_query(const float* __restrict__ xyz,
                                                 const float* __restrict__ new_xyz,
                                                 const float* __restrict__ view_rot,
                                                 int* __restrict__ idx_out) {
#pragma clang fp contract(off)
    int q = blockIdx.x;
    int b = q >> 10;                 // S_ = 1024
    int t = threadIdx.x;
    int w = t >> 6, lane = t & 63;

    __shared__ int lists[4][NS_];
    __shared__ int cnts[4];

    const float* nq = new_xyz + (size_t)q * 3;
    float qx = nq[0], qy = nq[1], qz = nq[2];
    const float* rp = view_rot + (size_t)q * 9;
    float R[9];
#pragma unroll
    for (int i = 0; i < 9; ++i) R[i] = rp[i];
    float dq0 = (R[0]*qx + R[1]*qy) + R[2]*qz;
    float dq1 = (R[3]*qx + R[4]*qy) + R[5]*qz;
    float dq2 = (R[6]*qx + R[7]*qy) + R[8]*qz;

    int start = w * 5000;
    int end   = min(N_, start + 5000);
    int cnt = 0;
    const float* xb = xyz + (size_t)b * N_ * 3;

    for (int base = start; base < end && cnt < NS_; base += 64) {
        int p = base + lane;
        bool m = false;
        if (p < end) {
            const float* pp = xb + (size_t)p * 3;
            float px = pp[0], py = pp[1], pz = pp[2];
            float xr = ((R[0]*px + R[1]*py) + R[2]*pz) - dq0;
            float yr = ((R[3]*px + R[4]*py) + R[5]*pz) - dq1;
            float zr = ((R[6]*px + R[7]*py) + R[8]*pz) - dq2;
            m = ((yr*yr + zr*zr) < R2C) && (xr > HMINC) && (xr < HMAXC);
        }
        unsigned long long bal = __ballot(m);
        int below = __popcll(bal & ((1ull << lane) - 1ull));
        if (m) {
            int pos = cnt + below;
            if (pos < NS_) lists[w][pos] = p;
        }
        cnt += (int)__popcll(bal);
        if (cnt > NS_) cnt = NS_;
    }
    if (lane == 0) cnts[w] = cnt;
    __syncthreads();

    if (t == 0) {
        int buf[NS_]; int total = 0;
        for (int ww = 0; ww < 4 && total < NS_; ++ww)
            for (int i = 0; i < cnts[ww] && total < NS_; ++i)
                buf[total++] = lists[ww][i];
        int first = (total > 0) ? buf[0] : 0;
        for (int i = 0; i < NS_; ++i)
            idx_out[q * NS_ + i] = (i < total) ? buf[i] : first;
    }
}

// ---------------------------------------------------------------- gather + h0
// h0 row (q*16+n): [feat(256) | rot_xyz(3) | 0 x29]  (bf16, width 288)
__global__ __launch_bounds__(256) void build_h0(const float* __restrict__ xyz,
                                                const float* __restrict__ new_xyz,
                                                const float* __restrict__ view_rot,
                                                const unsigned short* __restrict__ feat_t,
                                                const int* __restrict__ idxs,
                                                unsigned short* __restrict__ h0) {
#pragma clang fp contract(off)
    int q = blockIdx.x;
    int b = q >> 10;
    int t = threadIdx.x;
    __shared__ int pidx[NS_];
    if (t < NS_) pidx[t] = idxs[q * NS_ + t];
    __syncthreads();

    // feature rows: 16 rows x 512B, uint4-coalesced (32 lanes x 16B per row)
#pragma unroll
    for (int pass = 0; pass < 2; ++pass) {
        int n = pass * 8 + (t >> 5);
        int p = pidx[n];
        uint4 v = *(const uint4*)(feat_t + ((size_t)(b * N_ + p)) * C_ + (t & 31) * 8);
        *(uint4*)(h0 + (size_t)(q * NS_ + n) * K1P + (t & 31) * 8) = v;
    }

    if (t < NS_) {
        int n = t, p = pidx[n];
        const float* pp = xyz + ((size_t)b * N_ + p) * 3;
        const float* nq = new_xyz + (size_t)q * 3;
        float dx = (pp[0] - nq[0]) / 0.05f;
        float dy = (pp[1] - nq[1]) / 0.05f;
        float dz = (pp[2] - nq[2]) / 0.05f;
        const float* rp = view_rot + (size_t)q * 9;
        float r0 = (dx * rp[0] + dy * rp[3]) + dz * rp[6];
        float r1 = (dx * rp[1] + dy * rp[4]) + dz * rp[7];
        float r2 = (dx * rp[2] + dy * rp[5]) + dz * rp[8];
        size_t row = (size_t)(q * NS_ + n) * K1P;
        h0[row + 256] = f2b(r0);
        h0[row + 257] = f2b(r1);
        h0[row + 258] = f2b(r2);
    }
    for (int e = t; e < NS_ * 29; e += 256) {          // zero pad cols 259..287
        int n = e / 29, c = 259 + (e - n * 29);
        h0[(size_t)(q * NS_ + n) * K1P + c] = 0;
    }
}

// ---------------------------------------------------------------- MFMA GEMM + BN + ReLU
typedef float f32x4 __attribute__((ext_vector_type(4)));
typedef short s16x8 __attribute__((ext_vector_type(8)));

__global__ __launch_bounds__(256) void gemm_bn_relu(const unsigned short* __restrict__ A,
                                                    const unsigned short* __restrict__ W,
                                                    const float* __restrict__ bias,
                                                    const float* __restrict__ gam,
                                                    const float* __restrict__ bet,
                                                    unsigned short* __restrict__ out,
                                                    int M, int Nn, int K) {
    __shared__ __align__(16) unsigned short As[128 * 32];
    __shared__ __align__(16) unsigned short Bs[128 * 32];
    int tid  = threadIdx.x;
    int lane = tid & 63, wave = tid >> 6;
    int m0 = blockIdx.x * 128, n0 = blockIdx.y * 128;
    int wm = (wave >> 1) * 64, wn = (wave & 1) * 64;

    f32x4 acc[4][4] = {};

    for (int k0 = 0; k0 < K; k0 += 32) {
        __syncthreads();
#pragma unroll
        for (int j = 0; j < 2; ++j) {
            int e = j * 256 + tid;
            int r = e >> 2, c8 = (e & 3) << 3;
            *(uint4*)&As[e * 8] = *(const uint4*)(A + (size_t)(m0 + r) * K + k0 + c8);
            *(uint4*)&Bs[e * 8] = *(const uint4*)(W + (size_t)(n0 + r) * K + k0 + c8);
        }
        __syncthreads();

        int kq = (lane >> 4) * 8, rr = lane & 15;
        s16x8 af[4], bfr[4];
#pragma unroll
        for (int i = 0; i < 4; ++i) af[i]  = *(const s16x8*)&As[(wm + i * 16 + rr) * 32 + kq];
#pragma unroll
        for (int j = 0; j < 4; ++j) bfr[j] = *(const s16x8*)&Bs[(wn + j * 16 + rr) * 32 + kq];
#pragma unroll
        for (int i = 0; i < 4; ++i)
#pragma unroll
            for (int j = 0; j < 4; ++j)
                acc[i][j] = __builtin_amdgcn_mfma_f32_16x16x32_bf16(af[i], bfr[j], acc[i][j], 0, 0, 0);
    }

    float inv = 1.0f / sqrtf(1.0f + 1e-5f);
    int col = lane & 15, rq = (lane >> 4) * 4;
#pragma unroll
    for (int j = 0; j < 4; ++j) {
        int n = n0 + wn + j * 16 + col;
        float sc = gam[n] * inv;
        float tb = bias[n] * sc + bet[n];
#pragma unroll
        for (int i = 0; i < 4; ++i) {
            int mbase = m0 + wm + i * 16 + rq;
#pragma unroll
            for (int r = 0; r < 4; ++r) {
                float v = acc[i][j][r] * sc + tb;
                v = fmaxf(v, 0.0f);
                out[(size_t)(mbase + r) * Nn + n] = f2b(v);
            }
        }
    }
}

// ---------------------------------------------------------------- MFMA GEMM + BN + ReLU + 16-row maxpool
__global__ __launch_bounds__(256) void gemm_bn_relu_maxpool(const unsigned short* __restrict__ A,
                                                            const unsigned short* __restrict__ W,
                                                            const float* __restrict__ bias,
                                                            const float* __restrict__ gam,
                                                            const float* __restrict__ bet,
                                                            unsigned short* __restrict__ hp,
                                                            int M, int Nn, int K) {
    __shared__ __align__(16) unsigned short As[128 * 32];
    __shared__ __align__(16) unsigned short Bs[128 * 32];
    int tid  = threadIdx.x;
    int lane = tid & 63, wave = tid >> 6;
    int m0 = blockIdx.x * 128, n0 = blockIdx.y * 128;
    int wm = (wave >> 1) * 64, wn = (wave & 1) * 64;

    f32x4 acc[4][4] = {};

    for (int k0 = 0; k0 < K; k0 += 32) {
        __syncthreads();
#pragma unroll
        for (int j = 0; j < 2; ++j) {
            int e = j * 256 + tid;
            int r = e >> 2, c8 = (e & 3) << 3;
            *(uint4*)&As[e * 8] = *(const uint4*)(A + (size_t)(m0 + r) * K + k0 + c8);
            *(uint4*)&Bs[e * 8] = *(const uint4*)(W + (size_t)(n0 + r) * K + k0 + c8);
        }
        __syncthreads();

        int kq = (lane >> 4) * 8, rr = lane & 15;
        s16x8 af[4], bfr[4];
#pragma unroll
        for (int i = 0; i < 4; ++i) af[i]  = *(const s16x8*)&As[(wm + i * 16 + rr) * 32 + kq];
#pragma unroll
        for (int j = 0; j < 4; ++j) bfr[j] = *(const s16x8*)&Bs[(wn + j * 16 + rr) * 32 + kq];
#pragma unroll
        for (int i = 0; i < 4; ++i)
#pragma unroll
            for (int j = 0; j < 4; ++j)
                acc[i][j] = __builtin_amdgcn_mfma_f32_16x16x32_bf16(af[i], bfr[j], acc[i][j], 0, 0, 0);
    }

    float inv = 1.0f / sqrtf(1.0f + 1e-5f);
    int col = lane & 15;
    int qbase = (m0 + wm) >> 4;                 // query index of i-tile 0
#pragma unroll
    for (int j = 0; j < 4; ++j) {
        int n = n0 + wn + j * 16 + col;
        float sc = gam[n] * inv;
        float tb = bias[n] * sc + bet[n];
#pragma unroll
        for (int i = 0; i < 4; ++i) {
            float mx = 0.0f;                    // relu floor
#pragma unroll
            for (int r = 0; r < 4; ++r)
                mx = fmaxf(mx, acc[i][j][r] * sc + tb);
            mx = fmaxf(mx, __shfl_xor(mx, 16, 64));
            mx = fmaxf(mx, __shfl_xor(mx, 32, 64));
            if (lane < 16)
                hp[(size_t)(qbase + i) * Nn + n] = f2b(mx);
        }
    }
}

// ---------------------------------------------------------------- c3 GEMM: fp32 out, no BN/relu, N=96 (padded 128)
__global__ __launch_bounds__(256) void gemm_c3(const unsigned short* __restrict__ A,
                                               const unsigned short* __restrict__ W,
                                               const float* __restrict__ bias,
                                               float* __restrict__ out,
                                               int M, int K) {
    __shared__ __align__(16) unsigned short As[128 * 32];
    __shared__ __align__(16) unsigned short Bs[128 * 32];
    int tid  = threadIdx.x;
    int lane = tid & 63, wave = tid >> 6;
    int m0 = blockIdx.x * 128;
    int wm = (wave >> 1) * 64, wn = (wave & 1) * 64;

    f32x4 acc[4][4] = {};

    for (int k0 = 0; k0 < K; k0 += 32) {
        __syncthreads();
#pragma unroll
        for (int j = 0; j < 2; ++j) {
            int e = j * 256 + tid;
            int r = e >> 2, c8 = (e & 3) << 3;
            *(uint4*)&As[e * 8] = *(const uint4*)(A + (size_t)(m0 + r) * K + k0 + c8);
            *(uint4*)&Bs[e * 8] = *(const uint4*)(W + (size_t)r * K + k0 + c8);
        }
        __syncthreads();

        int kq = (lane >> 4) * 8, rr = lane & 15;
        s16x8 af[4], bfr[4];
#pragma unroll
        for (int i = 0; i < 4; ++i) af[i]  = *(const s16x8*)&As[(wm + i * 16 + rr) * 32 + kq];
#pragma unroll
        for (int j = 0; j < 4; ++j) bfr[j] = *(const s16x8*)&Bs[(wn + j * 16 + rr) * 32 + kq];
#pragma unroll
        for (int i = 0; i < 4; ++i)
#pragma unroll
            for (int j = 0; j < 4; ++j)
                acc[i][j] = __builtin_amdgcn_mfma_f32_16x16x32_bf16(af[i], bfr[j], acc[i][j], 0, 0, 0);
    }

    int col = lane & 15, rq = (lane >> 4) * 4;
#pragma unroll
    for (int j = 0; j < 4; ++j) {
        int n = wn + j * 16 + col;
        if (n >= OUTC) continue;
        float bb = bias[n];
#pragma unroll
        for (int i = 0; i < 4; ++i) {
            int mbase = m0 + wm + i * 16 + rq;
#pragma unroll
            for (int r = 0; r < 4; ++r)
                out[(size_t)(mbase + r) * OUTC + n] = acc[i][j][r] + bb;
        }
    }
}

// ---------------------------------------------------------------- launch
extern "C" void kernel_launch(void* const* d_in, const int* in_sizes, int n_in,
                              void* d_out, int out_size, void* d_ws, size_t ws_size,
                              hipStream_t stream) {
    const float* xyz      = (const float*)d_in[0];
    const float* new_xyz  = (const float*)d_in[1];
    const float* view_rot = (const float*)d_in[2];
    const float* feat     = (const float*)d_in[3];
    const float* m1w = (const float*)d_in[4];
    const float* m1b = (const float*)d_in[5];
    const float* m1g = (const float*)d_in[6];
    const float* m1be= (const float*)d_in[7];
    const float* m2w = (const float*)d_in[8];
    const float* m2b = (const float*)d_in[9];
    const float* m2g = (const float*)d_in[10];
    const float* m2be= (const float*)d_in[11];
    const float* m3w = (const float*)d_in[12];
    const float* m3b = (const float*)d_in[13];
    const float* m3g = (const float*)d_in[14];
    const float* m3be= (const float*)d_in[15];
    const float* c1w = (const float*)d_in[16];
    const float* c1b = (const float*)d_in[17];
    const float* c1g = (const float*)d_in[18];
    const float* c1be= (const float*)d_in[19];
    const float* c2w = (const float*)d_in[20];
    const float* c2b = (const float*)d_in[21];
    const float* c2g = (const float*)d_in[22];
    const float* c2be= (const float*)d_in[23];
    const float* c3w = (const float*)d_in[24];
    const float* c3b = (const float*)d_in[25];

    char* ws = (char*)d_ws;
    // layout (16B-aligned), total 53,248,000 B:
    //   [0, 131072)            idx  (2048*16 int32)
    //   [131072, 425984)       W1 padded bf16 (512*288), column-permuted
    //   [425984, 688128)       W2 bf16 (256*512)
    //   [688128, 819200)       W3 bf16 (256*256)
    //   [819200, 19693568)     h0 (32768*288 bf16) -> reused as h2 (32768*256)
    //   [19693568, 53248000)   h1 region (33.5 MB), time-multiplexed:
    //     phase A (pre-gemm1):  +12 MB  feat_t (2*20000*256 bf16 = 20.48 MB)
    //     phase B (gemm1 out):  h1 (32768*512 bf16 = 33.55 MB)
    //     phase C (post-gemm2): +0 hp | +4MB g1 | +8MB g2 | +12MB c1wb | +13MB c2wb | +14MB c3wb
    int*            idxs = (int*)ws;
    unsigned short* w1p  = (unsigned short*)(ws + 131072);
    unsigned short* w2p  = (unsigned short*)(ws + 425984);
    unsigned short* w3p  = (unsigned short*)(ws + 688128);
    unsigned short* h0   = (unsigned short*)(ws + 819200);
    char*           h1b  = ws + 19693568;
    unsigned short* h1   = (unsigned short*)h1b;
    unsigned short* h2   = h0;   // h0 dead after gemm1
    unsigned short* featt= (unsigned short*)(h1b + 12582912);
    unsigned short* hp   = (unsigned short*)(h1b + 0);
    unsigned short* g1   = (unsigned short*)(h1b + 4194304);
    unsigned short* g2   = (unsigned short*)(h1b + 8388608);
    unsigned short* c1wb = (unsigned short*)(h1b + 12582912);
    unsigned short* c2wb = (unsigned short*)(h1b + 13631488);
    unsigned short* c3wb = (unsigned short*)(h1b + 14680064);

    hipLaunchKernelGGL(prep_w123, dim3((O1 * K1P + O2 * 512 + O3 * 256) / 256), dim3(256), 0, stream,
                       m1w, m2w, m3w, w1p, w2p, w3p);
    hipLaunchKernelGGL(cyl_query, dim3(NQ), dim3(256), 0, stream, xyz, new_xyz, view_rot, idxs);
    hipLaunchKernelGGL(transpose_feat, dim3(N_ / 32, C_ / 32, B_), dim3(256), 0, stream, feat, featt);
    hipLaunchKernelGGL(build_h0, dim3(NQ), dim3(256), 0, stream, xyz, new_xyz, view_rot, featt, idxs, h0);
    hipLaunchKernelGGL(gemm_bn_relu, dim3(M_ / 128, O1 / 128), dim3(256), 0, stream,
                       h0, w1p, m1b, m1g, m1be, h1, M_, O1, K1P);
    hipLaunchKernelGGL(gemm_bn_relu, dim3(M_ / 128, O2 / 128), dim3(256), 0, stream,
                       h1, w2p, m2b, m2g, m2be, h2, M_, O2, 512);
    hipLaunchKernelGGL(prep_head_w, dim3(163840 / 256), dim3(256), 0, stream,
                       c1w, c2w, c3w, c1wb, c2wb, c3wb);
    hipLaunchKernelGGL(gemm_bn_relu_maxpool, dim3(M_ / 128, O3 / 128), dim3(256), 0, stream,
                       h2, w3p, m3b, m3g, m3be, hp, M_, O3, 256);
    hipLaunchKernelGGL(gemm_bn_relu, dim3(NQ / 128, 256 / 128), dim3(256), 0, stream,
                       hp, c1wb, c1b, c1g, c1be, g1, NQ, 256, 256);
    hipLaunchKernelGGL(gemm_bn_relu, dim3(NQ / 128, 256 / 128), dim3(256), 0, stream,
                       g1, c2wb, c2b, c2g, c2be, g2, NQ, 256, 256);
    hipLaunchKernelGGL(gemm_c3, dim3(NQ / 128), dim3(256), 0, stream,
                       g2, c3wb, c3b, (float*)d_out, NQ, 256);
}